// Round 10
// baseline (24.781 us; speedup 1.0000x reference)
//
#include <hip/hip_runtime.h>
#include <math.h>

// SphericalBessel in revolution-space: arg = r*k/(2pi); s,c via raw v_sin/v_cos
// (no internal 1/2pi mul); w = rcp(arg) = 2pi/x with all 2pi/S2PI factors folded
// into compile-time poly coefficients:  out = (kv*w) * [s*w*SG(w^2) + c*GM(w^2)]
// (odd L; even L symmetric). Small-x handled by clamping arg to xcut/(2pi):
// output becomes S2PI*kv*j_l(xcut), |err| <= ~4e-3 abs (budget 2.17e-2).
// Per-mode k-data from a 100-entry LDS float2 table (broadcast ds_read_b64) --
// removes the per-mode s_load batching stalls (SGPR_Count=32 -> not hoistable).

static constexpr int KMODES  = 100;
static constexpr int NTILE   = 64;
static constexpr int LSTRIDE = 102;   // even: 8B-aligned flush quads; writes 4-way (ok, LDS idle)
static constexpr double PI_D   = 3.14159265358979323846;
static constexpr double BETA_D = 1.0 / (2.0 * PI_D);          // 1/(2pi)
static constexpr double S2PI_D = 0.79788456080286535588;      // sqrt(2/pi)

__device__ __forceinline__ float rcpf(float x) { return __builtin_amdgcn_rcpf(x); }
__device__ __forceinline__ float sin_rev(float a) { float r; asm("v_sin_f32 %0, %1" : "=v"(r) : "v"(a)); return r; }
__device__ __forceinline__ float cos_rev(float a) { float r; asm("v_cos_f32 %0, %1" : "=v"(r) : "v"(a)); return r; }

// raw integer closed-form z-polys (z = 1/x^2), highest degree first (R4-verified)
template<int L> struct ZC;
template<> struct ZC<2>{ static constexpr double sg[2]={3,-1};                              static constexpr double gm[1]={-3}; };
template<> struct ZC<3>{ static constexpr double sg[2]={15,-6};                             static constexpr double gm[2]={-15,1}; };
template<> struct ZC<4>{ static constexpr double sg[3]={105,-45,1};                         static constexpr double gm[2]={-105,10}; };
template<> struct ZC<5>{ static constexpr double sg[3]={945,-420,15};                       static constexpr double gm[3]={-945,105,-1}; };
template<> struct ZC<6>{ static constexpr double sg[4]={10395,-4725,210,-1};                static constexpr double gm[3]={-10395,1260,-21}; };
template<> struct ZC<7>{ static constexpr double sg[4]={135135,-62370,3150,-28};            static constexpr double gm[4]={-135135,17325,-378,1}; };
template<> struct ZC<8>{ static constexpr double sg[5]={2027025,-945945,51975,-630,1};      static constexpr double gm[4]={-2027025,270270,-6930,36}; };
template<> struct ZC<9>{ static constexpr double sg[5]={34459425,-16216200,945945,-13860,45}; static constexpr double gm[5]={-34459425,4729725,-135135,990,-1}; };

// w-space scaled coefficients, generated constexpr (no narrowing, exact f64 folds):
// odd  L: out=(kv*w)*[s*w*SG(y) + c*GM(y)], y=w^2; SG_j = S2PI*sg_j*beta^(2deg+2), GM_j = S2PI*gm_j*beta^(2deg+1)
// even L: out=(kv*w)*[c*w*GM(y) + s*SG(y)];        SG_j = S2PI*sg_j*beta^(2deg+1), GM_j = S2PI*gm_j*beta^(2deg+2)
template<int L> struct WC {
  static constexpr int NS = L / 2 + 1, NG = (L + 1) / 2;
  float sg[NS], gm[NG], xc;
  constexpr WC() : sg{}, gm{}, xc(0.f) {
    constexpr double XT[10] = {0,0,0.088,0.29,0.61,1.01,1.48,2.00,2.55,3.14};
    for (int i = 0; i < NS; ++i) {
      int deg = NS - 1 - i, e = (L & 1) ? (2*deg + 2) : (2*deg + 1);
      double s = S2PI_D; for (int t = 0; t < e; ++t) s *= BETA_D;
      sg[i] = (float)(s * ZC<L>::sg[i]);
    }
    for (int i = 0; i < NG; ++i) {
      int deg = NG - 1 - i, e = (L & 1) ? (2*deg + 1) : (2*deg + 2);
      double s = S2PI_D; for (int t = 0; t < e; ++t) s *= BETA_D;
      gm[i] = (float)(s * ZC<L>::gm[i]);
    }
    xc = (float)(XT[L] * BETA_D);   // clamp point in revolutions
  }
};

template<int N>
__device__ __forceinline__ float polyH(float y, const float (&a)[N]) {
  float h = a[0];
#pragma unroll
  for (int i = 1; i < N; ++i) h = fmaf(h, y, a[i]);
  return h;
}

template<int L>
__device__ __forceinline__ void do_l(float rv, const float2* __restrict__ ktab,
                                     float* ldsrow) {
#pragma unroll
  for (int m = 0; m < 2 * L + 1; ++m) {
    const int KK = L * L + m;
    float2 kp = ktab[KK];              // broadcast ds_read_b64: {kv*beta, kv}
    float arg = rv * kp.x;             // x in revolutions
    float res;
    if constexpr (L == 0) {
      float w = rcpf(arg);
      float s = sin_rev(arg);
      res = (s * (float)(S2PI_D * BETA_D)) * (kp.y * w);   // S2PI*kv*sin(x)/x
    } else if constexpr (L == 1) {
      float w = rcpf(arg);
      float s = sin_rev(arg), c = cos_rev(arg);
      float t = c * (float)(S2PI_D * BETA_D);
      float inner = fmaf(s * w, (float)(S2PI_D * BETA_D * BETA_D), -t);
      res = (kp.y * w) * inner;
    } else {
      constexpr WC<L> wc{};
      float argc = fmaxf(arg, wc.xc);  // clamp: j_l(xcut) below cutoff, no select
      float w = rcpf(argc);
      float s = sin_rev(argc), c = cos_rev(argc);
      float y = w * w;
      float sgv = polyH(y, wc.sg);
      float gmv = polyH(y, wc.gm);
      float inner;
      if constexpr (L & 1) inner = fmaf(s * w, sgv, c * gmv);
      else                 inner = fmaf(c * w, gmv, s * sgv);
      res = (kp.y * w) * inner;
    }
    ldsrow[KK] = res;
  }
}

__global__ __launch_bounds__(256) void sbf_kernel(const float* __restrict__ r,
                                                  const float* __restrict__ kvec,
                                                  float* __restrict__ out) {
  __shared__ float2 ktab[KMODES];          // 800 B
  __shared__ float lds[NTILE * LSTRIDE];   // 26.1 KB; total 26.9 KB -> 6 blocks/CU
  const int tid = threadIdx.x;
  const int w = tid >> 6, lane = tid & 63;
  const int n0 = blockIdx.x * NTILE;
  if (tid < KMODES) {
    float kv = kvec[tid];
    ktab[tid] = make_float2(kv * (float)BETA_D, kv);
  }
  float rv = r[n0 + lane];
  float* ldsrow = &lds[lane * LSTRIDE];
  __syncthreads();                          // ktab ready
  // cost-balanced l-partition (issue model: 456/456/461/480)
  if (w == 0)      { do_l<9>(rv, ktab, ldsrow); do_l<2>(rv, ktab, ldsrow); }
  else if (w == 1) { do_l<8>(rv, ktab, ldsrow); do_l<3>(rv, ktab, ldsrow); }
  else if (w == 2) { do_l<7>(rv, ktab, ldsrow); do_l<4>(rv, ktab, ldsrow); do_l<0>(rv, ktab, ldsrow); }
  else             { do_l<6>(rv, ktab, ldsrow); do_l<5>(rv, ktab, ldsrow); do_l<1>(rv, ktab, ldsrow); }
  __syncthreads();
  // flush (R9-verified): contiguous float4 global stores; LDS float2-pair gather,
  // padded-row word index tracked incrementally (e += 1024 -> +10 rows, +24 cols)
  unsigned e0 = (unsigned)tid * 4u;
  int row = (int)(e0 / 100u);
  int col = (int)e0 - row * 100;
  int wi  = row * LSTRIDE + col;
  float* gout = out + (size_t)n0 * KMODES + e0;
#pragma unroll
  for (int it = 0; it < 6; ++it) {
    float2 lo = *reinterpret_cast<const float2*>(&lds[wi]);
    float2 hi = *reinterpret_cast<const float2*>(&lds[wi + 2]);
    *reinterpret_cast<float4*>(gout + it * 1024) = make_float4(lo.x, lo.y, hi.x, hi.y);
    col += 24; wi += 1044;
    if (col >= 100) { col -= 100; wi += 2; }
  }
  if (tid < 64) {
    float2 lo = *reinterpret_cast<const float2*>(&lds[wi]);
    float2 hi = *reinterpret_cast<const float2*>(&lds[wi + 2]);
    *reinterpret_cast<float4*>(gout + 6 * 1024) = make_float4(lo.x, lo.y, hi.x, hi.y);
  }
}

extern "C" void kernel_launch(void* const* d_in, const int* in_sizes, int n_in,
                              void* d_out, int out_size, void* d_ws, size_t ws_size,
                              hipStream_t stream) {
  const float* r = (const float*)d_in[0];
  const float* k = (const float*)d_in[1];
  float* out = (float*)d_out;
  int N = in_sizes[0];                   // 262144
  int blocks = N / NTILE;                // 4096
  sbf_kernel<<<blocks, 256, 0, stream>>>(r, k, out);
}